// Round 10
// baseline (552.549 us; speedup 1.0000x reference)
//
#include <hip/hip_runtime.h>

#define Hm 2048
#define Em 64
#define Tm 32768
#define KSEL 640        // int(1.25 * 32768 / 64)
#define CHK 32          // k per staged chunk
#define NTOK 64         // tokens per block in partial GEMM

typedef unsigned int u32;

__device__ __forceinline__ float4 ld4(const float* p) {
    return *reinterpret_cast<const float4*>(p);
}

// ---------------------------------------------------------------------------
// K0: W [64][2048] -> Wt [2048][64] (k-major, one-time)
// ---------------------------------------------------------------------------
__global__ __launch_bounds__(256) void k_wt(
    const float* __restrict__ W, float* __restrict__ Wt)
{
    __shared__ float T[64][65];
    const int tid = threadIdx.x;
    const int kb = blockIdx.x * 64;
    const int lc = tid & 63;
    const int lr = tid >> 6;
#pragma unroll
    for (int r = 0; r < 16; ++r) {
        const int e = r * 4 + lr;
        T[e][lc] = W[(size_t)e * Hm + kb + lc];
    }
    __syncthreads();
#pragma unroll
    for (int r = 0; r < 16; ++r) {
        const int kk = r * 4 + lr;
        Wt[(size_t)(kb + kk) * Em + lc] = T[lc][kk];
    }
}

// ---------------------------------------------------------------------------
// K1: split-K partial GEMM, LDS-cold design.
// grid = 512*nkq blocks x 128 threads (2 waves). Block = 64 tokens x 64 exp;
// wave = 64 tok (lane=token) x 32 exp; acc = 32 VGPR.
// W: lane-uniform float4 loads (1 txn, L1-resident) -> VGPR broadcast feeding
//    v_fmac directly. VMEM:FMA = 8:32 per kk (R3 failed at 16:16 scalar).
// A: LDS used ONLY as coalescing buffer, double-buffered, XOR-swizzled
//    (slot = g ^ (row&7)) on both write and read -> ~8-way worst alias.
// ---------------------------------------------------------------------------
__global__ __launch_bounds__(128, 2) void k_router_partial(
    const float* __restrict__ hid, const float* __restrict__ Wt,
    float* __restrict__ pl, int nkq)
{
    __shared__ __align__(16) float Ab[2][NTOK * CHK];   // 2 x 8 KB

    const int t    = threadIdx.x;
    const int lane = t & 63;          // token within block
    const int wv   = t >> 6;          // wave 0/1
    const int e0   = wv * 32;         // expert base
    const int tb   = blockIdx.x & 511;
    const int kq   = blockIdx.x >> 9;
    const int t0   = tb * NTOK;
    const int kslice = Hm / nkq;
    const int k0   = kq * kslice;
    const int nch  = kslice / CHK;

    // staging map: thread covers row sr (token), 16 floats at group base sh
    const int sr  = t >> 1;
    const int sh  = (t & 1) * 4;      // g index base: 0 or 4
    const int ssw = sr & 7;
    const float* ap = hid + (size_t)(t0 + sr) * Hm + k0;

    float acc[32];
#pragma unroll
    for (int j = 0; j < 32; ++j) acc[j] = 0.f;

    float4 sreg[4];
    auto loadS = [&](int c) {
#pragma unroll
        for (int u = 0; u < 4; ++u)
            sreg[u] = ld4(ap + c * CHK + (sh + u) * 4);
    };
    auto writeS = [&](int b) {
        float* base = &Ab[b][0];
#pragma unroll
        for (int u = 0; u < 4; ++u) {
            const int g = sh + u;
            *reinterpret_cast<float4*>(base + sr * CHK + ((g ^ ssw) * 4)) =
                sreg[u];
        }
    };

    const int lsw = lane & 7;

    loadS(0);
    writeS(0);
    __syncthreads();

    for (int c = 0; c < nch; ++c) {
        if (c + 1 < nch) loadS(c + 1);

        const float* base  = &Ab[c & 1][0];
        const float* wbase = Wt + (size_t)(k0 + c * CHK) * Em + e0;

#pragma unroll
        for (int g = 0; g < 8; ++g) {
            const float4 a4 = ld4(base + lane * CHK + ((g ^ lsw) * 4));
            const float av[4] = { a4.x, a4.y, a4.z, a4.w };
#pragma unroll
            for (int q = 0; q < 4; ++q) {
                const float* wr = wbase + (size_t)(g * 4 + q) * Em;
                float wvv[32];
#pragma unroll
                for (int x = 0; x < 8; ++x) {
                    const float4 wq = ld4(wr + 4 * x);
                    wvv[4 * x + 0] = wq.x; wvv[4 * x + 1] = wq.y;
                    wvv[4 * x + 2] = wq.z; wvv[4 * x + 3] = wq.w;
                }
#pragma unroll
                for (int j = 0; j < 32; ++j)
                    acc[j] = fmaf(av[q], wvv[j], acc[j]);
            }
        }

        if (c + 1 < nch) writeS((c + 1) & 1);
        __syncthreads();
    }

    // epilogue: lane = token, acc = experts e0..e0+31
    {
        float* dst = pl + ((size_t)kq * Tm + t0 + lane) * Em + e0;
#pragma unroll
        for (int x = 0; x < 8; ++x)
            *reinterpret_cast<float4*>(dst + 4 * x) =
                make_float4(acc[4 * x], acc[4 * x + 1],
                            acc[4 * x + 2], acc[4 * x + 3]);
    }
}

// ---------------------------------------------------------------------------
// K1b: reduce split-K partials + softmax. One thread per token.
// ---------------------------------------------------------------------------
__global__ __launch_bounds__(128) void k_reduce(
    const float* __restrict__ pl, int nkq,
    float* __restrict__ probs, float* __restrict__ probsT)
{
    const int t = blockIdx.x * 128 + threadIdx.x;
    float lg[64];
    {
        const float* src = pl + (size_t)t * Em;
#pragma unroll
        for (int j = 0; j < 16; ++j) {
            const float4 x = ld4(src + 4 * j);
            lg[4 * j + 0] = x.x; lg[4 * j + 1] = x.y;
            lg[4 * j + 2] = x.z; lg[4 * j + 3] = x.w;
        }
    }
    for (int q = 1; q < nkq; ++q) {
        const float* src = pl + ((size_t)q * Tm + t) * Em;
#pragma unroll
        for (int j = 0; j < 16; ++j) {
            const float4 x = ld4(src + 4 * j);
            lg[4 * j + 0] += x.x; lg[4 * j + 1] += x.y;
            lg[4 * j + 2] += x.z; lg[4 * j + 3] += x.w;
        }
    }
    float mx = lg[0];
#pragma unroll
    for (int e = 1; e < 64; ++e) mx = fmaxf(mx, lg[e]);
    float s = 0.f;
#pragma unroll
    for (int e = 0; e < 64; ++e) { lg[e] = __expf(lg[e] - mx); s += lg[e]; }
    const float inv = 1.0f / s;
#pragma unroll
    for (int e = 0; e < 64; ++e) lg[e] *= inv;

    float* po = probs + (size_t)t * Em;
#pragma unroll
    for (int j = 0; j < 16; ++j)
        *reinterpret_cast<float4*>(po + 4 * j) =
            make_float4(lg[4 * j], lg[4 * j + 1], lg[4 * j + 2], lg[4 * j + 3]);
#pragma unroll
    for (int e = 0; e < 64; ++e)
        probsT[(size_t)e * Tm + t] = lg[e];
}

// ---------------------------------------------------------------------------
// K2: per-expert top-640 radix select, passes 11/11/10 bits.
// No key staging; 16 wave-private 2048-bin histograms for pass 1.
// ---------------------------------------------------------------------------
__device__ __forceinline__ void suffix_scan_fast(u32* h, u32* wsum, int nbins) {
    const int tid  = threadIdx.x;
    const int lane = tid & 63;
    const int w    = tid >> 6;
    u32 a0, a1, s;
    if (nbins == 2048) {
        a0 = h[2 * tid]; a1 = h[2 * tid + 1]; s = a0 + a1;
    } else {
        a0 = h[tid]; a1 = 0; s = a0;
    }
    u32 v = s;
#pragma unroll
    for (int off = 1; off < 64; off <<= 1) {
        const u32 tv = __shfl_down(v, off, 64);
        if (lane + off < 64) v += tv;
    }
    if (lane == 0) wsum[w] = v;
    __syncthreads();
    u32 woff = 0;
#pragma unroll
    for (int j = 0; j < 16; ++j) woff += (j > w) ? wsum[j] : 0u;
    const u32 after = v - s + woff;
    if (nbins == 2048) {
        h[2 * tid]     = after + s;
        h[2 * tid + 1] = after + a1;
    } else {
        h[tid] = after + s;
    }
    __syncthreads();
}

__global__ __launch_bounds__(1024) void k_select(
    const float* __restrict__ probsT, float* __restrict__ dT)
{
    __shared__ u32 hist[16][2048];   // 128 KB
    __shared__ u32 tielist[2048];    // 8 KB
    __shared__ u32 wsum[16];
    __shared__ u32 sh_need[4];
    __shared__ u32 sh_bins[3];
    __shared__ u32 sh_ntie, sh_take, sh_nlist;

    const int tid = threadIdx.x;
    const int wv  = tid >> 6;
    const int e   = blockIdx.x;
    const float*  row  = probsT + (size_t)e * Tm;
    const float4* row4 = reinterpret_cast<const float4*>(row);

    {
        u32* hf = &hist[0][0];
        const uint4 z = make_uint4(0, 0, 0, 0);
#pragma unroll
        for (int k = 0; k < 8; ++k)
            *reinterpret_cast<uint4*>(&hf[4 * (tid + k * 1024)]) = z;
    }
    if (tid == 0) sh_need[0] = KSEL;
    __syncthreads();

    // pass 1: bits [31:21], wave-private
    {
        u32* myh = hist[wv];
        for (int i = tid; i < Tm / 4; i += 1024) {
            const float4 x = row4[i];
            atomicAdd(&myh[__float_as_uint(x.x) >> 21], 1u);
            atomicAdd(&myh[__float_as_uint(x.y) >> 21], 1u);
            atomicAdd(&myh[__float_as_uint(x.z) >> 21], 1u);
            atomicAdd(&myh[__float_as_uint(x.w) >> 21], 1u);
        }
    }
    __syncthreads();
    {
        u32 t0 = 0, t1 = 0;
#pragma unroll
        for (int w2 = 0; w2 < 16; ++w2) {
            t0 += hist[w2][tid];
            t1 += hist[w2][tid + 1024];
        }
        __syncthreads();
        hist[0][tid] = t0; hist[0][tid + 1024] = t1;
        __syncthreads();
    }
    suffix_scan_fast(hist[0], wsum, 2048);
    {
        const u32 need = sh_need[0];
#pragma unroll
        for (int r = 0; r < 2; ++r) {
            const int b = tid + r * 1024;
            const u32 sb = hist[0][b];
            const u32 sa = (b + 1 < 2048) ? hist[0][b + 1] : 0u;
            if (sb >= need && sa < need) { sh_bins[0] = (u32)b; sh_need[1] = need - sa; }
        }
    }
    __syncthreads();
    const u32 b1 = sh_bins[0];

    // pass 2: bits [20:10]
    hist[1][tid] = 0; hist[1][tid + 1024] = 0;
    __syncthreads();
    for (int i = tid; i < Tm; i += 1024) {
        const u32 k = __float_as_uint(row[i]);
        if ((k >> 21) == b1) atomicAdd(&hist[1][(k >> 10) & 0x7FFu], 1u);
    }
    __syncthreads();
    suffix_scan_fast(hist[1], wsum, 2048);
    {
        const u32 need = sh_need[1];
#pragma unroll
        for (int r = 0; r < 2; ++r) {
            const int b = tid + r * 1024;
            const u32 sb = hist[1][b];
            const u32 sa = (b + 1 < 2048) ? hist[1][b + 1] : 0u;
            if (sb >= need && sa < need) { sh_bins[1] = (u32)b; sh_need[2] = need - sa; }
        }
    }
    __syncthreads();
    const u32 p2 = (b1 << 11) | sh_bins[1];

    // pass 3: bits [9:0]
    hist[2][tid & 1023] = 0;
    __syncthreads();
    for (int i = tid; i < Tm; i += 1024) {
        const u32 k = __float_as_uint(row[i]);
        if ((k >> 10) == p2) atomicAdd(&hist[2][k & 0x3FFu], 1u);
    }
    __syncthreads();
    suffix_scan_fast(hist[2], wsum, 1024);
    if (tid < 1024) {
        const u32 need = sh_need[2];
        const u32 sb = hist[2][tid];
        const u32 sa = (tid + 1 < 1024) ? hist[2][tid + 1] : 0u;
        if (sb >= need && sa < need) {
            sh_bins[2] = (u32)tid;
            sh_take = need - sa;
            sh_ntie = sb - sa;
        }
    }
    __syncthreads();
    const u32 Kstar = (p2 << 10) | sh_bins[2];
    const u32 take = sh_take, ntie = sh_ntie;

    float4* drow4 = reinterpret_cast<float4*>(dT + (size_t)e * Tm);
    if (ntie == take) {
        for (int i = tid; i < Tm / 4; i += 1024) {
            const float4 x = row4[i];
            float4 o;
            o.x = (__float_as_uint(x.x) >= Kstar) ? x.x : 0.f;
            o.y = (__float_as_uint(x.y) >= Kstar) ? x.y : 0.f;
            o.z = (__float_as_uint(x.z) >= Kstar) ? x.z : 0.f;
            o.w = (__float_as_uint(x.w) >= Kstar) ? x.w : 0.f;
            drow4[i] = o;
        }
    } else {
        float* drow = dT + (size_t)e * Tm;
        if (tid == 0) sh_nlist = 0;
        __syncthreads();
        for (int i = tid; i < Tm; i += 1024) {
            const float v = row[i];
            const u32 k = __float_as_uint(v);
            drow[i] = (k > Kstar) ? v : 0.f;
            if (k == Kstar) {
                const u32 idx = atomicAdd(&sh_nlist, 1u);
                if (idx < 2048u) tielist[idx] = (u32)i;
            }
        }
        __syncthreads();
        const int n = (int)(sh_nlist < 2048u ? sh_nlist : 2048u);
        for (int i = tid; i < n; i += 1024) {
            const u32 tt = tielist[i];
            int r = 0;
            for (int j = 0; j < n; ++j) r += (tielist[j] < tt);
            if (r < (int)take) drow[tt] = __uint_as_float(Kstar);
        }
    }
}

// ---------------------------------------------------------------------------
// K3: transpose dT [E][T] -> dispatch [T][E] + combine, fused.
// ---------------------------------------------------------------------------
__global__ __launch_bounds__(256) void k_finish(
    const float* __restrict__ dT, float* __restrict__ dispatch,
    float* __restrict__ combine)
{
    __shared__ float Ls[64][65];
    const int tid = threadIdx.x;
    const int t0 = blockIdx.x * 64;
    {
        const int e = tid >> 2, tq = tid & 3;
        const float* src = dT + (size_t)e * Tm + t0 + tq * 16;
#pragma unroll
        for (int u = 0; u < 4; ++u) {
            const float4 x = ld4(src + 4 * u);
            Ls[tq * 16 + 4 * u + 0][e] = x.x;
            Ls[tq * 16 + 4 * u + 1][e] = x.y;
            Ls[tq * 16 + 4 * u + 2][e] = x.z;
            Ls[tq * 16 + 4 * u + 3][e] = x.w;
        }
    }
    __syncthreads();
    const int t = tid >> 2, q = tid & 3;
    float v[16];
    float s = 0.f;
#pragma unroll
    for (int u = 0; u < 16; ++u) { v[u] = Ls[t][q * 16 + u]; s += v[u]; }
    s += __shfl_xor(s, 1, 4);
    s += __shfl_xor(s, 2, 4);
    const float inv = (s > 0.f) ? 1.0f / s : 0.f;
    float* dp = dispatch + (size_t)(t0 + t) * Em + q * 16;
    float* cb = combine  + (size_t)(t0 + t) * Em + q * 16;
#pragma unroll
    for (int u = 0; u < 4; ++u) {
        *reinterpret_cast<float4*>(dp + 4 * u) =
            make_float4(v[4 * u], v[4 * u + 1], v[4 * u + 2], v[4 * u + 3]);
        *reinterpret_cast<float4*>(cb + 4 * u) =
            make_float4(v[4 * u] * inv, v[4 * u + 1] * inv,
                        v[4 * u + 2] * inv, v[4 * u + 3] * inv);
    }
}

// ---------------------------------------------------------------------------
extern "C" void kernel_launch(void* const* d_in, const int* in_sizes, int n_in,
                              void* d_out, int out_size, void* d_ws, size_t ws_size,
                              hipStream_t stream) {
    const float* hid = (const float*)d_in[0];
    const float* W   = (const float*)d_in[1];
    float* out      = (float*)d_out;
    float* dispatch = out;
    float* combine  = out + (size_t)Tm * Em;
    float* probs    = out + 2 * (size_t)Tm * Em;

    const size_t wtB = sizeof(float) * (size_t)Hm * Em;   // 512 KB
    const size_t teB = sizeof(float) * (size_t)Tm * Em;   // 8 MB
    char* ws = (char*)d_ws;

    float* Wt = (float*)ws;
    size_t off = wtB;

    // split-K factor: 4 preferred (grid 2048 = 8 blocks/CU in one round)
    int nkq = 1;
    if      (ws_size >= off + (4 + 2) * teB) nkq = 4;
    else if (ws_size >= off + (2 + 2) * teB) nkq = 2;

    float* pl = (float*)(ws + off);
    off += (size_t)nkq * teB;
    float* probsT = (float*)(ws + off); off += teB;
    float* dT     = (float*)(ws + off); off += teB;

    k_wt<<<Hm / 64, 256, 0, stream>>>(W, Wt);
    k_router_partial<<<(Tm / NTOK) * nkq, 128, 0, stream>>>(hid, Wt, pl, nkq);
    k_reduce<<<Tm / 128, 128, 0, stream>>>(pl, nkq, probs, probsT);
    k_select<<<Em, 1024, 0, stream>>>(probsT, dT);
    k_finish<<<Tm / 64, 256, 0, stream>>>(dT, dispatch, combine);
}